// Round 13
// baseline (31.206 us; speedup 1.0000x reference)
//
#include <hip/hip_runtime.h>
#include <hip/hip_bf16.h>

typedef __attribute__((ext_vector_type(8))) short short8;
typedef __attribute__((ext_vector_type(4))) float f32x4;

// bf16 truncation (round-toward-zero). Safe: s = ||z3||^2 cancels exactly in
// out = s*d / max(s*sqrt(n1*n2), eps); only d,n1,n2 (pure f32) reach out.
__device__ __forceinline__ unsigned int bfhi(float f) {
    return __builtin_bit_cast(unsigned int, f);
}
__device__ __forceinline__ unsigned int pack2(float lo, float hi) {
    return (bfhi(lo) >> 16) | (bfhi(hi) & 0xffff0000u);
}
__device__ __forceinline__ short8 pack_bf8(float4 a, float4 b) {
    uint4 u;
    u.x = pack2(a.x, a.y);
    u.y = pack2(a.z, a.w);
    u.z = pack2(b.x, b.y);
    u.w = pack2(b.z, b.w);
    return __builtin_bit_cast(short8, u);
}

// K0: convert W1/W2/W3 f32 -> bf16 into ws (vectorized x4).
// ushort layout: W1b @ 0 (98304), W2b @ 98304 (8192), W3b @ 106496 (2048).
__global__ __launch_bounds__(256) void cvt_weights(
    const float* __restrict__ W1, const float* __restrict__ W2,
    const float* __restrict__ W3, unsigned short* __restrict__ wsb)
{
    int i4 = (blockIdx.x * 256 + threadIdx.x) * 4;
    const float* src;
    int off;
    if (i4 < 98304)       { src = W1; off = 0; }
    else if (i4 < 106496) { src = W2; off = 98304; }
    else                  { src = W3; off = 106496; }
    float4 v = *(const float4*)(src + (i4 - off));
    uint2 u;
    u.x = pack2(v.x, v.y);
    u.y = pack2(v.z, v.w);
    *(uint2*)&wsb[i4] = u;
}

// K1: heterogeneous, LDS-free GEMM1. 512 blocks x 512 threads, LDS ~7KB.
//   bid 0..255  (Q): 16 rows. GEMM1 M=16,N=128,K=768 with A read DIRECTLY
//     from global X (2 float4/lane/k-step, packed to bf16 in-register; the 8
//     waves share the same 48KB of X via L1/L2) and B from bf16 wsb (short8).
//     NO LDS, NO barriers, no bank conflicts in the 24-step loop; iterations
//     independent -> deep pipelining. Then z1 -> LDS (barrier), GEMM2
//     (waves 0-3), GEMM3 (waves 0-1), s = ||z3||^2 -> wsf.
//   bid 256..511 (P): 16 rows (half-wave = row): 12 float4/lane up-front,
//     butterfly-reduce d, n1, n2 -> wsf.  (Proven ~1.1us/block-set pattern.)
// wsf (f32): d@0, n1@4096, n2@8192, s@12288. wsb (ushort) at wsf+16384.
__global__ __launch_bounds__(512, 4) void pq_kernel(
    const float* __restrict__ X,
    const unsigned short* __restrict__ wsb,
    const float* __restrict__ b1,
    const float* __restrict__ b2,
    const float* __restrict__ b3,
    float* __restrict__ wsf)
{
    __shared__ __align__(16) unsigned short z1[16][136];
    __shared__ __align__(16) unsigned short z2[16][72];
    __shared__ float sred[2][16];

    const int tid  = threadIdx.x;
    const int wid  = tid >> 6;
    const int lane = tid & 63;
    const int l15  = lane & 15;
    const int l4   = lane >> 4;

    if (blockIdx.x >= 256) {
        // ================= P path =================
        const int row = (int)(blockIdx.x - 256) * 16 + 2 * wid + (lane >> 5);
        const int ln  = lane & 31;
        const float4* b4 = (const float4*)(X + (size_t)row * 2304);
        float4 p1[6], p2[6];
#pragma unroll
        for (int m = 0; m < 6; ++m) p1[m] = b4[192 + ln + 32 * m];
#pragma unroll
        for (int m = 0; m < 6; ++m) p2[m] = b4[384 + ln + 32 * m];
        float dd = 0.f, aa = 0.f, bb = 0.f;
#pragma unroll
        for (int m = 0; m < 6; ++m) {
            float4 x = p1[m], y = p2[m];
            dd += x.x * y.x + x.y * y.y + x.z * y.z + x.w * y.w;
            aa += x.x * x.x + x.y * x.y + x.z * x.z + x.w * x.w;
            bb += y.x * y.x + y.y * y.y + y.z * y.z + y.w * y.w;
        }
#pragma unroll
        for (int m = 1; m < 32; m <<= 1) {
            dd += __shfl_xor(dd, m);
            aa += __shfl_xor(aa, m);
            bb += __shfl_xor(bb, m);
        }
        if (ln == 0) {
            wsf[row]        = dd;
            wsf[4096 + row] = aa;
            wsf[8192 + row] = bb;
        }
        return;
    }

    // ================= Q path =================
    const int row0 = (int)blockIdx.x * 16;
    const unsigned short* W1b = wsb;
    const unsigned short* W2b = wsb + 98304;
    const unsigned short* W3b = wsb + 106496;

    // ---- GEMM1: z1 = relu(Xq @ W1^T + b1), M=16, N=128, K=768 ----
    // wave w: cols 16w..16w+15. A straight from global, B bf16 from wsb.
    {
        f32x4 acc = {0.f, 0.f, 0.f, 0.f};
        const float* ap = X + (size_t)(row0 + l15) * 2304 + l4 * 8;
        const unsigned short* bp = W1b + (size_t)(16 * wid + l15) * 768 + l4 * 8;
#pragma unroll
        for (int it = 0; it < 24; ++it) {
            float4 a0 = *(const float4*)(ap + it * 32);
            float4 a1 = *(const float4*)(ap + it * 32 + 4);
            short8 b  = *(const short8*)(bp + it * 32);
            acc = __builtin_amdgcn_mfma_f32_16x16x32_bf16(pack_bf8(a0, a1), b, acc, 0, 0, 0);
        }
        float bv = b1[16 * wid + l15];
#pragma unroll
        for (int r = 0; r < 4; ++r) {
            float v = fmaxf(acc[r] + bv, 0.f);
            z1[4 * l4 + r][16 * wid + l15] = (unsigned short)(bfhi(v) >> 16);
        }
    }
    __syncthreads();

    // ---- GEMM2: z2 = relu(z1 @ W2^T + b2), M=16, N=64, K=128 (waves 0-3) ----
    if (wid < 4) {
        f32x4 acc = {0.f, 0.f, 0.f, 0.f};
        const unsigned short* bp = W2b + (size_t)(16 * wid + l15) * 128 + l4 * 8;
#pragma unroll
        for (int ks = 0; ks < 4; ++ks) {
            short8 a = *(const short8*)&z1[l15][ks * 32 + l4 * 8];
            short8 b = *(const short8*)(bp + ks * 32);
            acc = __builtin_amdgcn_mfma_f32_16x16x32_bf16(a, b, acc, 0, 0, 0);
        }
        float bv = b2[16 * wid + l15];
#pragma unroll
        for (int r = 0; r < 4; ++r) {
            float v = fmaxf(acc[r] + bv, 0.f);
            z2[4 * l4 + r][16 * wid + l15] = (unsigned short)(bfhi(v) >> 16);
        }
    }
    __syncthreads();

    // ---- GEMM3: z3 = relu(z2 @ W3^T + b3), M=16, N=32, K=64 (waves 0-1); s ----
    if (wid < 2) {
        f32x4 acc = {0.f, 0.f, 0.f, 0.f};
        const unsigned short* bp = W3b + (size_t)(16 * wid + l15) * 64 + l4 * 8;
#pragma unroll
        for (int ks = 0; ks < 2; ++ks) {
            short8 a = *(const short8*)&z2[l15][ks * 32 + l4 * 8];
            short8 b = *(const short8*)(bp + ks * 32);
            acc = __builtin_amdgcn_mfma_f32_16x16x32_bf16(a, b, acc, 0, 0, 0);
        }
        float bv = b3[16 * wid + l15];
        float sv[4];
#pragma unroll
        for (int r = 0; r < 4; ++r) {
            float v = fmaxf(acc[r] + bv, 0.f);
            sv[r] = v * v;
        }
#pragma unroll
        for (int m = 1; m < 16; m <<= 1)
#pragma unroll
            for (int r = 0; r < 4; ++r) sv[r] += __shfl_xor(sv[r], m);
        if (l15 == 0)
#pragma unroll
            for (int r = 0; r < 4; ++r) sred[wid][4 * l4 + r] = sv[r];
    }
    __syncthreads();
    if (tid < 16) wsf[12288 + row0 + tid] = sred[0][tid] + sred[1][tid];
}

// K2: combine. out = s*d / max(s*sqrt(n1*n2), eps)
__global__ __launch_bounds__(512) void combine(
    const float* __restrict__ wsf, float* __restrict__ out)
{
    int i = blockIdx.x * 512 + threadIdx.x;
    float d  = wsf[i];
    float n1 = wsf[4096 + i];
    float n2 = wsf[8192 + i];
    float s  = wsf[12288 + i];
    out[i] = (s * d) / fmaxf(s * sqrtf(n1 * n2), 1e-8f);
}

extern "C" void kernel_launch(void* const* d_in, const int* in_sizes, int n_in,
                              void* d_out, int out_size, void* d_ws, size_t ws_size,
                              hipStream_t stream)
{
    (void)in_sizes; (void)n_in; (void)out_size; (void)ws_size;
    const float* X  = (const float*)d_in[0];
    const float* W1 = (const float*)d_in[1];
    const float* b1 = (const float*)d_in[2];
    const float* W2 = (const float*)d_in[3];
    const float* b2 = (const float*)d_in[4];
    const float* W3 = (const float*)d_in[5];
    const float* b3 = (const float*)d_in[6];

    float* wsf          = (float*)d_ws;                   // d, n1, n2, s (4x4096)
    unsigned short* wsb = (unsigned short*)(wsf + 16384); // bf16 weights

    cvt_weights<<<dim3(106), dim3(256), 0, stream>>>(W1, W2, W3, wsb);
    pq_kernel<<<dim3(512), dim3(512), 0, stream>>>(X, wsb, b1, b2, b3, wsf);
    combine<<<dim3(8), dim3(512), 0, stream>>>(wsf, (float*)d_out);
}